// Round 5
// baseline (868.120 us; speedup 1.0000x reference)
//
#include <hip/hip_runtime.h>
#include <math.h>

// Net: ConvLSTM(32)->pool->ConvLSTM(48)->pool->conv3+ELU->conv4(1x1)+ELU->conv5(1x1)
// B=8, T=32, H=8, W=256, F1=32, F2=48, F3=256, F4=128, NNOTE=88
// R5: lstm1 wave remap (mh x nt) -> 4x fewer LDS B-frag reads per CU
//     (9216 -> 2304 cyc/step). pool2 fused into lstm2 steps (triple-buffer h2).

#define DEVINL static __device__ __forceinline__
typedef __attribute__((ext_vector_type(8))) short short8;
typedef __attribute__((ext_vector_type(4))) float f32x4;

#define PLANE_W1 49152      // w1F elements per plane (3*8*4*4*16*8)
#define PLANE_W2 147456     // w2F (3*12*8*4*16*8)
#define PLANE_W3 2359296    // w3F (16*48*6*4*16*8)

DEVINL float sigm(float x) { return 1.0f / (1.0f + __expf(-x)); }
DEVINL float tanh_fast(float x) { return 1.0f - 2.0f / (__expf(2.0f * x) + 1.0f); }
DEVINL float elu(float x) { return x > 0.0f ? x : expm1f(x); }
DEVINL unsigned short bf16_rne(float v) {
    unsigned u = __float_as_uint(v);
    unsigned r = (u + 0x7FFF + ((u >> 16) & 1)) >> 16;
    return (unsigned short)r;
}
DEVINL float bf16_to_f(unsigned short h) { return __uint_as_float(((unsigned)h) << 16); }

// ---------------- LSTM1 fused step (MFMA) ----------------
// grid (4,8,8) = (xq, y, b), block 512 = 8 waves = (mh 2) x (nt 4).
// Wave (mh,nt): 4 M-tiles (mt = mh*4+j) at column tile nt -> each B-frag pair
// feeds 12 MFMA (4 mt x 3 terms). C/D: col=lane&15, row=kg*4+reg; lane holds
// gates i/f/g/o of f = mt*4+kg. Pool of pair (t-2,t-1) fused at even t.
__global__ __launch_bounds__(512) void lstm1_step(
    const float* __restrict__ xin,           // (8,1,32,8,256)
    const unsigned short* __restrict__ w1F,  // hi plane + lo plane
    const float* __restrict__ b1,            // (128)
    const float* __restrict__ hprev,         // h1[(t+2)%3]
    const float* __restrict__ hpoolA,        // h1[(t+1)%3] = t-2's h
    float* __restrict__ hout,                // h1[t%3]
    float* __restrict__ c1,                  // (8,32,8,256)
    unsigned short* __restrict__ p1hi, unsigned short* __restrict__ p1lo,
    int t)
{
    __shared__ __align__(16) unsigned short sBhi[66 * 128];
    __shared__ __align__(16) unsigned short sBlo[66 * 128];
    const int xq = blockIdx.x, y = blockIdx.y, b = blockIdx.z;
    const int x0 = xq * 64;
    const int tid = threadIdx.x;

    // fused pool of pair (t-2, t-1) -> p1[tp], done by odd-y blocks
    if (((t & 1) == 0) && t >= 2 && (y & 1) == 1) {
        int tp = (t >> 1) - 1, yp = y >> 1;
        for (int e = tid; e < 1024; e += 512) {
            int f = e >> 5, xl = e & 31;
            int xp = (x0 >> 1) + xl, gx = x0 + 2 * xl;
            int b0 = ((b * 32 + f) * 8 + (y - 1)) * 256 + gx;
            float m = hpoolA[b0];
            m = fmaxf(m, hpoolA[b0 + 1]);
            m = fmaxf(m, hpoolA[b0 + 256]);
            m = fmaxf(m, hpoolA[b0 + 257]);
            m = fmaxf(m, hprev[b0]);
            m = fmaxf(m, hprev[b0 + 1]);
            m = fmaxf(m, hprev[b0 + 256]);
            m = fmaxf(m, hprev[b0 + 257]);
            int pi = (((b * 32 + f) * 16 + tp) * 4 + yp) * 128 + xp;
            unsigned short hi = bf16_rne(m);
            p1hi[pi] = hi;
            p1lo[pi] = bf16_rne(m - bf16_to_f(hi));
        }
    }

    // stage input tile as bf16 hi/lo, swizzled: slot' = (k>>3) ^ (lx&15)
    for (int e = tid; e < 66 * 128; e += 512) {
        int lx = e % 66, kk = e / 66;
        float v = 0.0f;
        if (kk < 99) {
            int ci = kk / 3, dy = kk - ci * 3;
            int gy = y + dy - 1, gx = x0 + lx - 1;
            if (gy >= 0 && gy < 8 && gx >= 0 && gx < 256)
                v = (ci == 0) ? xin[((b * 32 + t) * 8 + gy) * 256 + gx]
                              : hprev[((b * 32 + (ci - 1)) * 8 + gy) * 256 + gx];
        }
        unsigned short hi = bf16_rne(v);
        unsigned short lo = bf16_rne(v - bf16_to_f(hi));
        int a16 = lx * 128 + (((kk >> 3) ^ (lx & 15)) << 3) + (kk & 7);
        sBhi[a16] = hi;
        sBlo[a16] = lo;
    }
    __syncthreads();

    const int l = tid & 63;
    const int wv = __builtin_amdgcn_readfirstlane(tid >> 6);
    const int mh = wv >> 2, nt = wv & 3;
    const int ln = l & 15, kg = l >> 4;
    f32x4 acc[4];
#pragma unroll
    for (int j = 0; j < 4; ++j) acc[j] = (f32x4){0.f, 0.f, 0.f, 0.f};

#pragma unroll
    for (int kk = 0; kk < 4; ++kk) {
        short8 bh[3], bl[3];
#pragma unroll
        for (int dx = 0; dx < 3; ++dx) {
            int lx = nt * 16 + ln + dx;
            int slot = kk * 4 + kg;
            int boff = lx * 128 + ((slot ^ (lx & 15)) << 3);
            bh[dx] = *(const short8*)&sBhi[boff];
            bl[dx] = *(const short8*)&sBlo[boff];
        }
#pragma unroll
        for (int j = 0; j < 4; ++j) {
            int mt = mh * 4 + j;
#pragma unroll
            for (int dx = 0; dx < 3; ++dx) {
                int aoff = ((((dx * 8 + mt) * 4 + kk) * 4 + kg) * 16 + ln) * 8;
                short8 ah = *(const short8*)&w1F[aoff];
                short8 al = *(const short8*)&w1F[PLANE_W1 + aoff];
                acc[j] = __builtin_amdgcn_mfma_f32_16x16x32_bf16(al, bh[dx], acc[j], 0, 0, 0);
                acc[j] = __builtin_amdgcn_mfma_f32_16x16x32_bf16(ah, bl[dx], acc[j], 0, 0, 0);
                acc[j] = __builtin_amdgcn_mfma_f32_16x16x32_bf16(ah, bh[dx], acc[j], 0, 0, 0);
            }
        }
    }

#pragma unroll
    for (int j = 0; j < 4; ++j) {
        const int f = (mh * 4 + j) * 4 + kg;
        float zi = acc[j][0] + b1[f];
        float zf = acc[j][1] + b1[32 + f];
        float zg = acc[j][2] + b1[64 + f];
        float zo = acc[j][3] + b1[96 + f];
        int gidx = ((b * 32 + f) * 8 + y) * 256 + x0 + nt * 16 + ln;
        float cv = c1[gidx];
        float cn = sigm(zf) * cv + sigm(zi) * tanh_fast(zg);
        c1[gidx] = cn;
        hout[gidx] = sigm(zo) * tanh_fast(cn);
    }
}

// ---------------- final pool1 for tp=15 ----------------
__global__ void pool1k(const float* __restrict__ hA, const float* __restrict__ hB,
                       unsigned short* __restrict__ p1hi, unsigned short* __restrict__ p1lo,
                       int tp)
{
    int idx = blockIdx.x * 256 + threadIdx.x;
    if (idx >= 8 * 32 * 4 * 128) return;
    int xp = idx & 127, t1 = idx >> 7;
    int yp = t1 & 3, t2 = t1 >> 2;
    int f = t2 & 31, b = t2 >> 5;
    int base = ((b * 32 + f) * 8 + yp * 2) * 256 + xp * 2;
    float m = hA[base];
    m = fmaxf(m, hA[base + 1]);
    m = fmaxf(m, hA[base + 256]);
    m = fmaxf(m, hA[base + 257]);
    m = fmaxf(m, hB[base]);
    m = fmaxf(m, hB[base + 1]);
    m = fmaxf(m, hB[base + 256]);
    m = fmaxf(m, hB[base + 257]);
    int pi = (((b * 32 + f) * 16 + tp) * 4 + yp) * 128 + xp;
    unsigned short hi = bf16_rne(m);
    p1hi[pi] = hi;
    p1lo[pi] = bf16_rne(m - bf16_to_f(hi));
}

// ---------------- LSTM2 step (MFMA, gates fused, pool of prev pair fused) ----
// grid (8,4,8) = (xq, y, b), block 256 = 4 waves; wave wv owns mt = wv*3..wv*3+2.
// M=192 perm rows: row = (f>>2)*16 + (f&3)*4 + gate, co = gate*48+f.
// B staged [lx 0..17][k 0..255] (k=ci*3+dy, 240 used), XOR-swizzled.
// At even t>=2, y<2 blocks pool h2 pair (t-2,t-1) into p2[tp=(t>>1)-1].
__global__ __launch_bounds__(256) void lstm2_step(
    const unsigned short* __restrict__ p1hi, const unsigned short* __restrict__ p1lo,
    const unsigned short* __restrict__ w2F,  // hi plane + lo plane
    const float* __restrict__ b2,            // (192)
    const float* __restrict__ hprev,         // h2[(t+2)%3]
    const float* __restrict__ hpoolA,        // h2[(t+1)%3] = t-2's h
    float* __restrict__ c2,                  // (8,48,4,128)
    float* __restrict__ hout,                // h2[t%3]
    unsigned short* __restrict__ p2hi, unsigned short* __restrict__ p2lo,
    int t)
{
    __shared__ __align__(16) unsigned short sBhi[18 * 256];
    __shared__ __align__(16) unsigned short sBlo[18 * 256];
    const int xq = blockIdx.x, y = blockIdx.y, b = blockIdx.z;
    const int x0 = xq * 16;
    const int tid = threadIdx.x;

    // fused pool of h2 pair (t-2, t-1) -> p2[tp]; yp = y (<2), xp = xq*8..+7
    if (((t & 1) == 0) && t >= 2 && y < 2) {
        int tp = (t >> 1) - 1;
        for (int e = tid; e < 48 * 8; e += 256) {
            int f = e >> 3, xl = e & 7;
            int xp = xq * 8 + xl;
            int g0 = ((b * 48 + f) * 4 + y * 2) * 128 + xp * 2;
            float m = fmaxf(fmaxf(hpoolA[g0], hpoolA[g0 + 1]),
                            fmaxf(hpoolA[g0 + 128], hpoolA[g0 + 129]));
            m = fmaxf(m, fmaxf(fmaxf(hprev[g0], hprev[g0 + 1]),
                               fmaxf(hprev[g0 + 128], hprev[g0 + 129])));
            int pi = ((b * 48 + f) * 16 + tp * 2 + y) * 64 + xp;
            unsigned short hi = bf16_rne(m);
            p2hi[pi] = hi;
            p2lo[pi] = bf16_rne(m - bf16_to_f(hi));
        }
    }

    for (int idx = tid; idx < 80 * 54; idx += 256) {
        int ci = idx / 54, rem = idx % 54;
        int dy = rem / 18, lx = rem % 18;
        int gy = y + dy - 1, gx = x0 + lx - 1;
        unsigned short hi = 0, lo = 0;
        if (gy >= 0 && gy < 4 && gx >= 0 && gx < 128) {
            if (ci < 32) {
                int pi = (((b * 32 + ci) * 16 + t) * 4 + gy) * 128 + gx;
                hi = p1hi[pi];
                lo = p1lo[pi];
            } else {
                float v = hprev[((b * 48 + (ci - 32)) * 4 + gy) * 128 + gx];
                hi = bf16_rne(v);
                lo = bf16_rne(v - bf16_to_f(hi));
            }
        }
        int k = ci * 3 + dy;
        int a16 = lx * 256 + (((k >> 3) ^ (lx & 15)) << 3) + (k & 7);
        sBhi[a16] = hi;
        sBlo[a16] = lo;
    }
    // zero pad slots (k = 240..255)
    for (int e = tid; e < 18 * 16; e += 256) {
        int lx = e >> 4, k = 240 + (e & 15);
        int a16 = lx * 256 + (((k >> 3) ^ (lx & 15)) << 3) + (k & 7);
        sBhi[a16] = 0;
        sBlo[a16] = 0;
    }
    __syncthreads();

    const int l = tid & 63;
    const int wv = __builtin_amdgcn_readfirstlane(tid >> 6);
    const int ln = l & 15, kg = l >> 4;
    f32x4 acc[3] = {{0.f, 0.f, 0.f, 0.f}, {0.f, 0.f, 0.f, 0.f}, {0.f, 0.f, 0.f, 0.f}};

#pragma unroll
    for (int kk = 0; kk < 8; ++kk) {
        short8 bh[3], bl[3];
#pragma unroll
        for (int dx = 0; dx < 3; ++dx) {
            int lx = ln + dx;
            int boff = lx * 256 + ((((kk << 2) + kg) ^ (lx & 15)) << 3);
            bh[dx] = *(const short8*)&sBhi[boff];
            bl[dx] = *(const short8*)&sBlo[boff];
        }
#pragma unroll
        for (int j = 0; j < 3; ++j) {
            int mt = wv * 3 + j;
#pragma unroll
            for (int dx = 0; dx < 3; ++dx) {
                int aoff = ((((dx * 12 + mt) * 8 + kk) * 4 + kg) * 16 + ln) * 8;
                short8 ah = *(const short8*)&w2F[aoff];
                short8 al = *(const short8*)&w2F[PLANE_W2 + aoff];
                acc[j] = __builtin_amdgcn_mfma_f32_16x16x32_bf16(al, bh[dx], acc[j], 0, 0, 0);
                acc[j] = __builtin_amdgcn_mfma_f32_16x16x32_bf16(ah, bl[dx], acc[j], 0, 0, 0);
                acc[j] = __builtin_amdgcn_mfma_f32_16x16x32_bf16(ah, bh[dx], acc[j], 0, 0, 0);
            }
        }
    }

    const int x = x0 + ln;
#pragma unroll
    for (int j = 0; j < 3; ++j) {
        int mt = wv * 3 + j;
        int f = mt * 4 + kg;
        float zi = acc[j][0] + b2[f];
        float zf = acc[j][1] + b2[48 + f];
        float zg = acc[j][2] + b2[96 + f];
        float zo = acc[j][3] + b2[144 + f];
        int gidx = ((b * 48 + f) * 4 + y) * 128 + x;
        float cv = c2[gidx];
        float cn = sigm(zf) * cv + sigm(zi) * tanh_fast(zg);
        c2[gidx] = cn;
        hout[gidx] = sigm(zo) * tanh_fast(cn);
    }
}

// ---------------- final pool2 for tp=7 ----------------
__global__ void pool2(const float* __restrict__ hA, const float* __restrict__ hB,
                      unsigned short* __restrict__ p2hi, unsigned short* __restrict__ p2lo,
                      int tp)
{
    int idx = blockIdx.x * 256 + threadIdx.x;
    if (idx >= 8 * 48 * 2 * 64) return;
    int xp = idx & 63;
    int t1 = idx >> 6;
    int yp = t1 & 1; t1 >>= 1;
    int f = t1 % 48, b = t1 / 48;
    float m = -INFINITY;
#pragma unroll
    for (int dy = 0; dy < 2; ++dy)
#pragma unroll
        for (int dx = 0; dx < 2; ++dx) {
            int g = ((b * 48 + f) * 4 + yp * 2 + dy) * 128 + xp * 2 + dx;
            m = fmaxf(m, fmaxf(hA[g], hB[g]));
        }
    int pi = ((b * 48 + f) * 16 + tp * 2 + yp) * 64 + xp;
    unsigned short hi = bf16_rne(m);
    p2hi[pi] = hi;
    p2lo[pi] = bf16_rne(m - bf16_to_f(hi));
}

// ---------------- conv3 (streaming MFMA, K-split partials) ----------------
// grid (16 mq, 12 ck), block 256 = 4 waves; wave wv -> c = ck*4+wv.
// A = w3F fragment-linear; B = p2 planes, short8 loads with zero overfetch.
__global__ __launch_bounds__(256) void conv3_part(
    const unsigned short* __restrict__ p2hi, const unsigned short* __restrict__ p2lo,
    const unsigned short* __restrict__ w3F,
    float* __restrict__ part)    // (12,256,112)
{
    __shared__ float sRed[4 * 7 * 256];
    const int mq = blockIdx.x, ck = blockIdx.y;
    const int tid = threadIdx.x;
    const int l = tid & 63;
    const int wv = __builtin_amdgcn_readfirstlane(tid >> 6);
    const int c = ck * 4 + wv;
    const int ln = l & 15, kg = l >> 4;

    int rowbase[7];
#pragma unroll
    for (int nt = 0; nt < 7; ++nt) {
        int col = nt * 16 + ln;
        int bi = col / 14, r = col % 14;
        rowbase[nt] = (bi * 48 + c) * 16 + r;
    }

    f32x4 acc[7];
#pragma unroll
    for (int nt = 0; nt < 7; ++nt) acc[nt] = (f32x4){0.f, 0.f, 0.f, 0.f};

#pragma unroll
    for (int kk = 0; kk < 6; ++kk) {
        int aoff = ((((mq * 48 + c) * 6 + kk) * 4 + kg) * 16 + ln) * 8;
        short8 ah = *(const short8*)&w3F[aoff];
        short8 al = *(const short8*)&w3F[PLANE_W3 + aoff];
        int s = kk * 4 + kg;
        int dr = s >> 3, w0 = (s & 7) * 8;
#pragma unroll
        for (int nt = 0; nt < 7; ++nt) {
            int boff = (rowbase[nt] + dr) * 64 + w0;
            short8 bh = *(const short8*)&p2hi[boff];
            short8 bl = *(const short8*)&p2lo[boff];
            acc[nt] = __builtin_amdgcn_mfma_f32_16x16x32_bf16(al, bh, acc[nt], 0, 0, 0);
            acc[nt] = __builtin_amdgcn_mfma_f32_16x16x32_bf16(ah, bl, acc[nt], 0, 0, 0);
            acc[nt] = __builtin_amdgcn_mfma_f32_16x16x32_bf16(ah, bh, acc[nt], 0, 0, 0);
        }
    }

#pragma unroll
    for (int nt = 0; nt < 7; ++nt)
        *(f32x4*)&sRed[wv * 1792 + nt * 256 + l * 4] = acc[nt];
    __syncthreads();

#pragma unroll
    for (int nt = 0; nt < 7; ++nt) {
        float s = sRed[nt * 256 + tid] + sRed[1792 + nt * 256 + tid] +
                  sRed[2 * 1792 + nt * 256 + tid] + sRed[3 * 1792 + nt * 256 + tid];
        int r16 = (tid >> 6) * 4 + (tid & 3);
        int m = mq * 16 + r16;
        int col = nt * 16 + ((tid >> 2) & 15);
        part[(ck * 256 + m) * 112 + col] = s;
    }
}

// ---------------- head: reduce+bias+ELU -> conv4+ELU -> conv5 ----------------
// grid 112 = (b*14+r), block 256.
__global__ __launch_bounds__(256) void head(
    const float* __restrict__ part, const float* __restrict__ b3,
    const float* __restrict__ w4T, const float* __restrict__ b4,
    const float* __restrict__ w5T, const float* __restrict__ b5,
    float* __restrict__ out)
{
    __shared__ float sO3[256];
    __shared__ float sO4[128];
    const int col = blockIdx.x;          // b*14 + r
    const int b = col / 14, r = col % 14;
    const int tid = threadIdx.x;

    float s = b3[tid];
#pragma unroll
    for (int ck = 0; ck < 12; ++ck)
        s += part[(ck * 256 + tid) * 112 + col];
    sO3[tid] = elu(s);
    __syncthreads();

    if (tid < 128) {
        float a4 = b4[tid];
        for (int c = 0; c < 256; ++c)
            a4 = fmaf(sO3[c], w4T[c * 128 + tid], a4);
        sO4[tid] = elu(a4);
    }
    __syncthreads();

    if (tid < 88) {
        float a5 = b5[tid];
        for (int c = 0; c < 128; ++c)
            a5 = fmaf(sO4[c], w5T[c * 88 + tid], a5);
        out[(b * 88 + tid) * 14 + r] = a5;
    }
}

// ---------------- weight prepacks (fragment-linear, bf16 hi/lo) ----------------
__global__ void prep(const float* __restrict__ w1, const float* __restrict__ w2,
                     const float* __restrict__ w3, const float* __restrict__ w4,
                     const float* __restrict__ w5,
                     unsigned short* __restrict__ w1F, unsigned short* __restrict__ w2F,
                     unsigned short* __restrict__ w3F,
                     float* __restrict__ w4T, float* __restrict__ w5T)
{
    int idx = blockIdx.x * 256 + threadIdx.x;
    if (idx < PLANE_W1) {   // w1F[dx][mt 8][kk 4][kg][ln][8]
        int dx = idx / 16384, rem = idx % 16384;
        int mt = rem / 2048, r2 = rem % 2048;
        int kk = r2 / 512, r3 = r2 % 512;
        int kg = r3 / 128, r4 = r3 % 128;
        int ln = r4 / 8, e = r4 % 8;
        int f = mt * 4 + (ln >> 2), gate = ln & 3;
        int co = gate * 32 + f;
        int k = kk * 32 + kg * 8 + e;
        float v = 0.0f;
        if (k < 99) v = w1[co * 297 + (k / 3) * 9 + (k % 3) * 3 + dx];
        unsigned short hi = bf16_rne(v);
        w1F[idx] = hi;
        w1F[PLANE_W1 + idx] = bf16_rne(v - bf16_to_f(hi));
        return;
    }
    idx -= PLANE_W1;
    if (idx < PLANE_W2) {   // w2F[dx][mt 12][kk 8][kg][ln][8]
        int dx = idx / 49152, rem = idx % 49152;
        int mt = rem / 4096, r2 = rem % 4096;
        int kk = r2 / 512, r3 = r2 % 512;
        int kg = r3 / 128, r4 = r3 % 128;
        int ln = r4 / 8, e = r4 % 8;
        int f = mt * 4 + (ln >> 2), gate = ln & 3;
        int co = gate * 48 + f;
        int k = kk * 32 + kg * 8 + e;
        float v = 0.0f;
        if (k < 240) v = w2[co * 720 + (k / 3) * 9 + (k % 3) * 3 + dx];
        unsigned short hi = bf16_rne(v);
        w2F[idx] = hi;
        w2F[PLANE_W2 + idx] = bf16_rne(v - bf16_to_f(hi));
        return;
    }
    idx -= PLANE_W2;
    if (idx < PLANE_W3) {   // w3F[mq 16][c 48][kk 6][kg][ln][8]
        int mq = idx / 147456, rem = idx % 147456;
        int c = rem / 3072, r2 = rem % 3072;
        int kk = r2 / 512, r3 = r2 % 512;
        int kg = r3 / 128, r4 = r3 % 128;
        int ln = r4 / 8, e = r4 % 8;
        int m = mq * 16 + ln;
        int kc = kk * 32 + kg * 8 + e;
        int dr = kc >> 6, w = kc & 63;
        float v = w3[((m * 48 + c) * 3 + dr) * 64 + w];
        unsigned short hi = bf16_rne(v);
        w3F[idx] = hi;
        w3F[PLANE_W3 + idx] = bf16_rne(v - bf16_to_f(hi));
        return;
    }
    idx -= PLANE_W3;
    if (idx < 32768) {      // w4 (128,256) -> w4T (256,128)
        int n = idx / 256, cch = idx % 256;
        w4T[cch * 128 + n] = w4[idx];
        return;
    }
    idx -= 32768;
    if (idx < 11264) {      // w5 (88,128) -> w5T (128,88)
        int n = idx / 128, cch = idx % 128;
        w5T[cch * 88 + n] = w5[idx];
    }
}

extern "C" void kernel_launch(void* const* d_in, const int* in_sizes, int n_in,
                              void* d_out, int out_size, void* d_ws, size_t ws_size,
                              hipStream_t stream)
{
    const float* x  = (const float*)d_in[0];
    const float* w1 = (const float*)d_in[1];
    const float* b1 = (const float*)d_in[2];
    const float* w2 = (const float*)d_in[3];
    const float* b2 = (const float*)d_in[4];
    const float* w3 = (const float*)d_in[5];
    const float* b3 = (const float*)d_in[6];
    const float* w4 = (const float*)d_in[7];
    const float* b4 = (const float*)d_in[8];
    const float* w5 = (const float*)d_in[9];
    const float* b5 = (const float*)d_in[10];
    float* out = (float*)d_out;

    float* ws = (float*)d_ws;
    size_t off = 0;
    auto alloc = [&](size_t n) { float* p = ws + off; off += n; return p; };
    float* h1[3]; h1[0] = alloc(524288); h1[1] = alloc(524288); h1[2] = alloc(524288);
    float* c1 = alloc(524288);
    unsigned short* p1hi = (unsigned short*)alloc(1048576); // 2097152 u16
    unsigned short* p1lo = (unsigned short*)alloc(1048576);
    float* h2[3]; h2[0] = alloc(196608); h2[1] = alloc(196608); h2[2] = alloc(196608);
    float* c2 = alloc(196608);
    unsigned short* p2hi = (unsigned short*)alloc(196608);  // 393216 u16
    unsigned short* p2lo = (unsigned short*)alloc(196608);
    float* part = alloc(344064);          // (12,256,112)
    unsigned short* w1F = (unsigned short*)alloc(49152);    // 2 planes
    unsigned short* w2F = (unsigned short*)alloc(147456);
    unsigned short* w3F = (unsigned short*)alloc(2359296);
    float* w4T = alloc(32768);
    float* w5T = alloc(11264);
    (void)ws_size; (void)off;  // ~33 MB total

    hipMemsetAsync(h1[2], 0, 524288 * sizeof(float), stream);
    hipMemsetAsync(c1,    0, 524288 * sizeof(float), stream);
    hipMemsetAsync(h2[2], 0, 196608 * sizeof(float), stream);
    hipMemsetAsync(c2,    0, 196608 * sizeof(float), stream);

    prep<<<10156, 256, 0, stream>>>(w1, w2, w3, w4, w5, w1F, w2F, w3F, w4T, w5T);

    for (int t = 0; t < 32; ++t) {
        lstm1_step<<<dim3(4, 8, 8), 512, 0, stream>>>(
            x, w1F, b1, h1[(t + 2) % 3], h1[(t + 1) % 3], h1[t % 3], c1,
            p1hi, p1lo, t);
    }
    pool1k<<<512, 256, 0, stream>>>(h1[0], h1[1], p1hi, p1lo, 15); // t=30,31

    for (int t = 0; t < 16; ++t) {
        lstm2_step<<<dim3(8, 4, 8), 256, 0, stream>>>(
            p1hi, p1lo, w2F, b2, h2[(t + 2) % 3], h2[(t + 1) % 3], c2, h2[t % 3],
            p2hi, p2lo, t);
    }
    pool2<<<192, 256, 0, stream>>>(h2[2], h2[0], p2hi, p2lo, 7);   // t=14,15

    conv3_part<<<dim3(16, 12), 256, 0, stream>>>(p2hi, p2lo, w3F, part);
    head<<<112, 256, 0, stream>>>(part, b3, w4T, b4, w5T, b5, out);
}

// Round 6
// 662.686 us; speedup vs baseline: 1.3100x; 1.3100x over previous
//
#include <hip/hip_runtime.h>
#include <math.h>

// Net: ConvLSTM(32)->pool->ConvLSTM(48)->pool->conv3+ELU->conv4(1x1)+ELU->conv5(1x1)
// B=8, T=32, H=8, W=256, F1=32, F2=48, F3=256, F4=128, NNOTE=88
// R6: balanced lstm1 wave map (2 mt x 2 nt: A-L2 1.4us, B-LDS 1.9us, MFMA 1.55us);
//     A-operand hi-only (2-term split) in both LSTMs; p1 packed u32; fast prep.

#define DEVINL static __device__ __forceinline__
typedef __attribute__((ext_vector_type(8))) short short8;
typedef __attribute__((ext_vector_type(4))) float f32x4;

#define PLANE_W3 2359296    // w3F (16*48*6*4*16*8), hi plane size (lo follows)

DEVINL float sigm(float x) { return 1.0f / (1.0f + __expf(-x)); }
DEVINL float tanh_fast(float x) { return 1.0f - 2.0f / (__expf(2.0f * x) + 1.0f); }
DEVINL float elu(float x) { return x > 0.0f ? x : expm1f(x); }
DEVINL unsigned short bf16_rne(float v) {
    unsigned u = __float_as_uint(v);
    unsigned r = (u + 0x7FFF + ((u >> 16) & 1)) >> 16;
    return (unsigned short)r;
}
DEVINL float bf16_to_f(unsigned short h) { return __uint_as_float(((unsigned)h) << 16); }
DEVINL unsigned pack_hl(float v) {
    unsigned short hi = bf16_rne(v);
    unsigned short lo = bf16_rne(v - bf16_to_f(hi));
    return (unsigned)hi | ((unsigned)lo << 16);
}

// ---------------- LSTM1 fused step (MFMA, 2-term split) ----------------
// grid (4,8,8) = (xq, y, b), block 512 = 8 waves = (mh 4) x (nh 2).
// Wave (mh,nh): M-tiles {mh*2, mh*2+1} x N-tiles {nh*2, nh*2+1}.
// C/D: col=lane&15, row=kg*4+reg -> lane holds gates i/f/g/o of f = mt*4+kg.
// Pool of pair (t-2,t-1) fused at even t (odd-y blocks).
__global__ __launch_bounds__(512) void lstm1_step(
    const float* __restrict__ xin,           // (8,1,32,8,256)
    const unsigned short* __restrict__ w1F,  // hi only, [dx][mt][kk][kg][ln][8]
    const float* __restrict__ b1,            // (128)
    const float* __restrict__ hprev,         // h1[(t+2)%3]
    const float* __restrict__ hpoolA,        // h1[(t+1)%3] = t-2's h
    float* __restrict__ hout,                // h1[t%3]
    float* __restrict__ c1,                  // (8,32,8,256)
    unsigned* __restrict__ p1pk,             // (8,32,16,4,128) packed hi|lo<<16
    int t)
{
    __shared__ __align__(16) unsigned short sBhi[66 * 128];
    __shared__ __align__(16) unsigned short sBlo[66 * 128];
    const int xq = blockIdx.x, y = blockIdx.y, b = blockIdx.z;
    const int x0 = xq * 64;
    const int tid = threadIdx.x;

    // fused pool of pair (t-2, t-1) -> p1[tp], done by odd-y blocks
    if (((t & 1) == 0) && t >= 2 && (y & 1) == 1) {
        int tp = (t >> 1) - 1, yp = y >> 1;
        for (int e = tid; e < 1024; e += 512) {
            int f = e >> 5, xl = e & 31;
            int xp = (x0 >> 1) + xl, gx = x0 + 2 * xl;
            int b0 = ((b * 32 + f) * 8 + (y - 1)) * 256 + gx;
            float m = hpoolA[b0];
            m = fmaxf(m, hpoolA[b0 + 1]);
            m = fmaxf(m, hpoolA[b0 + 256]);
            m = fmaxf(m, hpoolA[b0 + 257]);
            m = fmaxf(m, hprev[b0]);
            m = fmaxf(m, hprev[b0 + 1]);
            m = fmaxf(m, hprev[b0 + 256]);
            m = fmaxf(m, hprev[b0 + 257]);
            p1pk[(((b * 32 + f) * 16 + tp) * 4 + yp) * 128 + xp] = pack_hl(m);
        }
    }

    // stage input tile as bf16 hi/lo, swizzled: slot' = (k>>3) ^ (lx&15)
    for (int e = tid; e < 66 * 128; e += 512) {
        int lx = e % 66, kk = e / 66;
        float v = 0.0f;
        if (kk < 99) {
            int ci = kk / 3, dy = kk - ci * 3;
            int gy = y + dy - 1, gx = x0 + lx - 1;
            if (gy >= 0 && gy < 8 && gx >= 0 && gx < 256)
                v = (ci == 0) ? xin[((b * 32 + t) * 8 + gy) * 256 + gx]
                              : hprev[((b * 32 + (ci - 1)) * 8 + gy) * 256 + gx];
        }
        unsigned short hi = bf16_rne(v);
        unsigned short lo = bf16_rne(v - bf16_to_f(hi));
        int a16 = lx * 128 + (((kk >> 3) ^ (lx & 15)) << 3) + (kk & 7);
        sBhi[a16] = hi;
        sBlo[a16] = lo;
    }
    __syncthreads();

    const int l = tid & 63;
    const int wv = __builtin_amdgcn_readfirstlane(tid >> 6);
    const int mh = wv >> 1, nh = wv & 1;
    const int ln = l & 15, kg = l >> 4;
    f32x4 acc[2][2];
#pragma unroll
    for (int i = 0; i < 2; ++i)
#pragma unroll
        for (int j = 0; j < 2; ++j) acc[i][j] = (f32x4){0.f, 0.f, 0.f, 0.f};

#pragma unroll
    for (int kk = 0; kk < 4; ++kk) {
        short8 bh[2][3], bl[2][3];
#pragma unroll
        for (int ntl = 0; ntl < 2; ++ntl)
#pragma unroll
            for (int dx = 0; dx < 3; ++dx) {
                int lx = (nh * 2 + ntl) * 16 + ln + dx;
                int slot = kk * 4 + kg;
                int boff = lx * 128 + ((slot ^ (lx & 15)) << 3);
                bh[ntl][dx] = *(const short8*)&sBhi[boff];
                bl[ntl][dx] = *(const short8*)&sBlo[boff];
            }
#pragma unroll
        for (int mtl = 0; mtl < 2; ++mtl)
#pragma unroll
            for (int dx = 0; dx < 3; ++dx) {
                int aoff = ((((dx * 8 + mh * 2 + mtl) * 4 + kk) * 4 + kg) * 16 + ln) * 8;
                short8 ah = *(const short8*)&w1F[aoff];
#pragma unroll
                for (int ntl = 0; ntl < 2; ++ntl) {
                    acc[mtl][ntl] = __builtin_amdgcn_mfma_f32_16x16x32_bf16(ah, bl[ntl][dx], acc[mtl][ntl], 0, 0, 0);
                    acc[mtl][ntl] = __builtin_amdgcn_mfma_f32_16x16x32_bf16(ah, bh[ntl][dx], acc[mtl][ntl], 0, 0, 0);
                }
            }
    }

#pragma unroll
    for (int mtl = 0; mtl < 2; ++mtl) {
        const int f = (mh * 2 + mtl) * 4 + kg;
        const float bi = b1[f], bff = b1[32 + f], bg = b1[64 + f], bo = b1[96 + f];
#pragma unroll
        for (int ntl = 0; ntl < 2; ++ntl) {
            f32x4 a = acc[mtl][ntl];
            int gidx = ((b * 32 + f) * 8 + y) * 256 + x0 + (nh * 2 + ntl) * 16 + ln;
            float zi = a[0] + bi, zf = a[1] + bff, zg = a[2] + bg, zo = a[3] + bo;
            float cv = c1[gidx];
            float cn = sigm(zf) * cv + sigm(zi) * tanh_fast(zg);
            c1[gidx] = cn;
            hout[gidx] = sigm(zo) * tanh_fast(cn);
        }
    }
}

// ---------------- final pool1 for tp=15 ----------------
__global__ void pool1k(const float* __restrict__ hA, const float* __restrict__ hB,
                       unsigned* __restrict__ p1pk, int tp)
{
    int idx = blockIdx.x * 256 + threadIdx.x;
    if (idx >= 8 * 32 * 4 * 128) return;
    int xp = idx & 127, t1 = idx >> 7;
    int yp = t1 & 3, t2 = t1 >> 2;
    int f = t2 & 31, b = t2 >> 5;
    int base = ((b * 32 + f) * 8 + yp * 2) * 256 + xp * 2;
    float m = hA[base];
    m = fmaxf(m, hA[base + 1]);
    m = fmaxf(m, hA[base + 256]);
    m = fmaxf(m, hA[base + 257]);
    m = fmaxf(m, hB[base]);
    m = fmaxf(m, hB[base + 1]);
    m = fmaxf(m, hB[base + 256]);
    m = fmaxf(m, hB[base + 257]);
    p1pk[(((b * 32 + f) * 16 + tp) * 4 + yp) * 128 + xp] = pack_hl(m);
}

// ---------------- LSTM2 step (MFMA, 2-term, gates + prev-pair pool fused) ----
// grid (8,4,8) = (xq, y, b), block 256 = 4 waves; wave wv owns mt = wv*3..wv*3+2.
__global__ __launch_bounds__(256) void lstm2_step(
    const unsigned* __restrict__ p1pk,
    const unsigned short* __restrict__ w2F,  // hi only, [dx][mt][kk][kg][ln][8]
    const float* __restrict__ b2,            // (192)
    const float* __restrict__ hprev,         // h2[(t+2)%3]
    const float* __restrict__ hpoolA,        // h2[(t+1)%3] = t-2's h
    float* __restrict__ c2,                  // (8,48,4,128)
    float* __restrict__ hout,                // h2[t%3]
    unsigned short* __restrict__ p2hi, unsigned short* __restrict__ p2lo,
    int t)
{
    __shared__ __align__(16) unsigned short sBhi[18 * 256];
    __shared__ __align__(16) unsigned short sBlo[18 * 256];
    const int xq = blockIdx.x, y = blockIdx.y, b = blockIdx.z;
    const int x0 = xq * 16;
    const int tid = threadIdx.x;

    if (((t & 1) == 0) && t >= 2 && y < 2) {
        int tp = (t >> 1) - 1;
        for (int e = tid; e < 48 * 8; e += 256) {
            int f = e >> 3, xl = e & 7;
            int xp = xq * 8 + xl;
            int g0 = ((b * 48 + f) * 4 + y * 2) * 128 + xp * 2;
            float m = fmaxf(fmaxf(hpoolA[g0], hpoolA[g0 + 1]),
                            fmaxf(hpoolA[g0 + 128], hpoolA[g0 + 129]));
            m = fmaxf(m, fmaxf(fmaxf(hprev[g0], hprev[g0 + 1]),
                               fmaxf(hprev[g0 + 128], hprev[g0 + 129])));
            int pi = ((b * 48 + f) * 16 + tp * 2 + y) * 64 + xp;
            unsigned short hi = bf16_rne(m);
            p2hi[pi] = hi;
            p2lo[pi] = bf16_rne(m - bf16_to_f(hi));
        }
    }

    for (int idx = tid; idx < 80 * 54; idx += 256) {
        int ci = idx / 54, rem = idx % 54;
        int dy = rem / 18, lx = rem % 18;
        int gy = y + dy - 1, gx = x0 + lx - 1;
        unsigned short hi = 0, lo = 0;
        if (gy >= 0 && gy < 4 && gx >= 0 && gx < 128) {
            if (ci < 32) {
                unsigned v = p1pk[(((b * 32 + ci) * 16 + t) * 4 + gy) * 128 + gx];
                hi = (unsigned short)v;
                lo = (unsigned short)(v >> 16);
            } else {
                float v = hprev[((b * 48 + (ci - 32)) * 4 + gy) * 128 + gx];
                hi = bf16_rne(v);
                lo = bf16_rne(v - bf16_to_f(hi));
            }
        }
        int k = ci * 3 + dy;
        int a16 = lx * 256 + (((k >> 3) ^ (lx & 15)) << 3) + (k & 7);
        sBhi[a16] = hi;
        sBlo[a16] = lo;
    }
    for (int e = tid; e < 18 * 16; e += 256) {
        int lx = e >> 4, k = 240 + (e & 15);
        int a16 = lx * 256 + (((k >> 3) ^ (lx & 15)) << 3) + (k & 7);
        sBhi[a16] = 0;
        sBlo[a16] = 0;
    }
    __syncthreads();

    const int l = tid & 63;
    const int wv = __builtin_amdgcn_readfirstlane(tid >> 6);
    const int ln = l & 15, kg = l >> 4;
    f32x4 acc[3] = {{0.f, 0.f, 0.f, 0.f}, {0.f, 0.f, 0.f, 0.f}, {0.f, 0.f, 0.f, 0.f}};

#pragma unroll
    for (int kk = 0; kk < 8; ++kk) {
        short8 bh[3], bl[3];
#pragma unroll
        for (int dx = 0; dx < 3; ++dx) {
            int lx = ln + dx;
            int boff = lx * 256 + ((((kk << 2) + kg) ^ (lx & 15)) << 3);
            bh[dx] = *(const short8*)&sBhi[boff];
            bl[dx] = *(const short8*)&sBlo[boff];
        }
#pragma unroll
        for (int j = 0; j < 3; ++j) {
            int mt = wv * 3 + j;
#pragma unroll
            for (int dx = 0; dx < 3; ++dx) {
                int aoff = ((((dx * 12 + mt) * 8 + kk) * 4 + kg) * 16 + ln) * 8;
                short8 ah = *(const short8*)&w2F[aoff];
                acc[j] = __builtin_amdgcn_mfma_f32_16x16x32_bf16(ah, bl[dx], acc[j], 0, 0, 0);
                acc[j] = __builtin_amdgcn_mfma_f32_16x16x32_bf16(ah, bh[dx], acc[j], 0, 0, 0);
            }
        }
    }

    const int x = x0 + ln;
#pragma unroll
    for (int j = 0; j < 3; ++j) {
        int mt = wv * 3 + j;
        int f = mt * 4 + kg;
        float zi = acc[j][0] + b2[f];
        float zf = acc[j][1] + b2[48 + f];
        float zg = acc[j][2] + b2[96 + f];
        float zo = acc[j][3] + b2[144 + f];
        int gidx = ((b * 48 + f) * 4 + y) * 128 + x;
        float cv = c2[gidx];
        float cn = sigm(zf) * cv + sigm(zi) * tanh_fast(zg);
        c2[gidx] = cn;
        hout[gidx] = sigm(zo) * tanh_fast(cn);
    }
}

// ---------------- final pool2 for tp=7 ----------------
__global__ void pool2(const float* __restrict__ hA, const float* __restrict__ hB,
                      unsigned short* __restrict__ p2hi, unsigned short* __restrict__ p2lo,
                      int tp)
{
    int idx = blockIdx.x * 256 + threadIdx.x;
    if (idx >= 8 * 48 * 2 * 64) return;
    int xp = idx & 63;
    int t1 = idx >> 6;
    int yp = t1 & 1; t1 >>= 1;
    int f = t1 % 48, b = t1 / 48;
    float m = -INFINITY;
#pragma unroll
    for (int dy = 0; dy < 2; ++dy)
#pragma unroll
        for (int dx = 0; dx < 2; ++dx) {
            int g = ((b * 48 + f) * 4 + yp * 2 + dy) * 128 + xp * 2 + dx;
            m = fmaxf(m, fmaxf(hA[g], hB[g]));
        }
    int pi = ((b * 48 + f) * 16 + tp * 2 + yp) * 64 + xp;
    unsigned short hi = bf16_rne(m);
    p2hi[pi] = hi;
    p2lo[pi] = bf16_rne(m - bf16_to_f(hi));
}

// ---------------- conv3 (streaming MFMA, 3-term, K-split partials) ----------
__global__ __launch_bounds__(256) void conv3_part(
    const unsigned short* __restrict__ p2hi, const unsigned short* __restrict__ p2lo,
    const unsigned short* __restrict__ w3F,
    float* __restrict__ part)    // (12,256,112)
{
    __shared__ float sRed[4 * 7 * 256];
    const int mq = blockIdx.x, ck = blockIdx.y;
    const int tid = threadIdx.x;
    const int l = tid & 63;
    const int wv = __builtin_amdgcn_readfirstlane(tid >> 6);
    const int c = ck * 4 + wv;
    const int ln = l & 15, kg = l >> 4;

    int rowbase[7];
#pragma unroll
    for (int nt = 0; nt < 7; ++nt) {
        int col = nt * 16 + ln;
        int bi = col / 14, r = col % 14;
        rowbase[nt] = (bi * 48 + c) * 16 + r;
    }

    f32x4 acc[7];
#pragma unroll
    for (int nt = 0; nt < 7; ++nt) acc[nt] = (f32x4){0.f, 0.f, 0.f, 0.f};

#pragma unroll
    for (int kk = 0; kk < 6; ++kk) {
        int aoff = ((((mq * 48 + c) * 6 + kk) * 4 + kg) * 16 + ln) * 8;
        short8 ah = *(const short8*)&w3F[aoff];
        short8 al = *(const short8*)&w3F[PLANE_W3 + aoff];
        int s = kk * 4 + kg;
        int dr = s >> 3, w0 = (s & 7) * 8;
#pragma unroll
        for (int nt = 0; nt < 7; ++nt) {
            int boff = (rowbase[nt] + dr) * 64 + w0;
            short8 bh = *(const short8*)&p2hi[boff];
            short8 bl = *(const short8*)&p2lo[boff];
            acc[nt] = __builtin_amdgcn_mfma_f32_16x16x32_bf16(al, bh, acc[nt], 0, 0, 0);
            acc[nt] = __builtin_amdgcn_mfma_f32_16x16x32_bf16(ah, bl, acc[nt], 0, 0, 0);
            acc[nt] = __builtin_amdgcn_mfma_f32_16x16x32_bf16(ah, bh, acc[nt], 0, 0, 0);
        }
    }

#pragma unroll
    for (int nt = 0; nt < 7; ++nt)
        *(f32x4*)&sRed[wv * 1792 + nt * 256 + l * 4] = acc[nt];
    __syncthreads();

#pragma unroll
    for (int nt = 0; nt < 7; ++nt) {
        float s = sRed[nt * 256 + tid] + sRed[1792 + nt * 256 + tid] +
                  sRed[2 * 1792 + nt * 256 + tid] + sRed[3 * 1792 + nt * 256 + tid];
        int r16 = (tid >> 6) * 4 + (tid & 3);
        int m = mq * 16 + r16;
        int col = nt * 16 + ((tid >> 2) & 15);
        part[(ck * 256 + m) * 112 + col] = s;
    }
}

// ---------------- head: reduce+bias+ELU -> conv4+ELU -> conv5 ----------------
__global__ __launch_bounds__(256) void head(
    const float* __restrict__ part, const float* __restrict__ b3,
    const float* __restrict__ w4T, const float* __restrict__ b4,
    const float* __restrict__ w5T, const float* __restrict__ b5,
    float* __restrict__ out)
{
    __shared__ float sO3[256];
    __shared__ float sO4[128];
    const int col = blockIdx.x;          // b*14 + r
    const int b = col / 14, r = col % 14;
    const int tid = threadIdx.x;

    float s = b3[tid];
#pragma unroll
    for (int ck = 0; ck < 12; ++ck)
        s += part[(ck * 256 + tid) * 112 + col];
    sO3[tid] = elu(s);
    __syncthreads();

    if (tid < 128) {
        float a4 = b4[tid];
        for (int c = 0; c < 256; ++c)
            a4 = fmaf(sO3[c], w4T[c * 128 + tid], a4);
        sO4[tid] = elu(a4);
    }
    __syncthreads();

    if (tid < 88) {
        float a5 = b5[tid];
        for (int c = 0; c < 128; ++c)
            a5 = fmaf(sO4[c], w5T[c * 88 + tid], a5);
        out[(b * 88 + tid) * 14 + r] = a5;
    }
}

// ---------------- weight prepacks (8-wide fragments per thread) --------------
// w1F/w2F: hi plane only. w3F: hi+lo. w4T/w5T: fp32 transposes.
__global__ void prep(const float* __restrict__ w1, const float* __restrict__ w2,
                     const float* __restrict__ w3, const float* __restrict__ w4,
                     const float* __restrict__ w5,
                     unsigned short* __restrict__ w1F, unsigned short* __restrict__ w2F,
                     unsigned short* __restrict__ w3F,
                     float* __restrict__ w4T, float* __restrict__ w5T)
{
    int i = blockIdx.x * 256 + threadIdx.x;
    if (i < 6144) {            // w1F hi: [dx][mt 8][kk 4][kg 4][ln 16][8]
        int base = i * 8;
        int dx = base / 16384, rem = base % 16384;
        int mt = rem / 2048, r2 = rem % 2048;
        int kk = r2 / 512, r3 = r2 % 512;
        int kg = r3 / 128, ln = (r3 % 128) / 8;
        int f = mt * 4 + (ln >> 2), gate = ln & 3;
        int co = gate * 32 + f;
        int k0 = kk * 32 + kg * 8;
        short8 h;
#pragma unroll
        for (int e = 0; e < 8; ++e) {
            int k = k0 + e;
            float v = (k < 99) ? w1[co * 297 + (k / 3) * 9 + (k % 3) * 3 + dx] : 0.0f;
            h[e] = (short)bf16_rne(v);
        }
        *(short8*)&w1F[base] = h;
        return;
    }
    i -= 6144;
    if (i < 18432) {           // w2F hi: [dx][mt 12][kk 8][kg 4][ln 16][8]
        int base = i * 8;
        int dx = base / 49152, rem = base % 49152;
        int mt = rem / 4096, r2 = rem % 4096;
        int kk = r2 / 512, r3 = r2 % 512;
        int kg = r3 / 128, ln = (r3 % 128) / 8;
        int f = mt * 4 + (ln >> 2), gate = ln & 3;
        int co = gate * 48 + f;
        int k0 = kk * 32 + kg * 8;
        short8 h;
#pragma unroll
        for (int e = 0; e < 8; ++e) {
            int k = k0 + e;
            float v = (k < 240) ? w2[co * 720 + (k / 3) * 9 + (k % 3) * 3 + dx] : 0.0f;
            h[e] = (short)bf16_rne(v);
        }
        *(short8*)&w2F[base] = h;
        return;
    }
    i -= 18432;
    if (i < 294912) {          // w3F hi+lo: [mq 16][c 48][kk 6][kg 4][ln 16][8]
        int base = i * 8;
        int mq = base / 147456, rem = base % 147456;
        int c = rem / 3072, r2 = rem % 3072;
        int kk = r2 / 512, r3 = r2 % 512;
        int kg = r3 / 128, ln = (r3 % 128) / 8;
        int m = mq * 16 + ln;
        int kc0 = kk * 32 + kg * 8;
        int dr = kc0 >> 6, w0 = kc0 & 63;
        const float* src = &w3[((m * 48 + c) * 3 + dr) * 64 + w0];
        short8 hh, hl;
#pragma unroll
        for (int e = 0; e < 8; ++e) {
            float v = src[e];
            unsigned short hi = bf16_rne(v);
            hh[e] = (short)hi;
            hl[e] = (short)bf16_rne(v - bf16_to_f(hi));
        }
        *(short8*)&w3F[base] = hh;
        *(short8*)&w3F[PLANE_W3 + base] = hl;
        return;
    }
    i -= 294912;
    if (i < 32768) {           // w4 (128,256) -> w4T (256,128)
        int n = i / 256, cch = i % 256;
        w4T[cch * 128 + n] = w4[i];
        return;
    }
    i -= 32768;
    if (i < 11264) {           // w5 (88,128) -> w5T (128,88)
        int n = i / 128, cch = i % 128;
        w5T[cch * 88 + n] = w5[i];
    }
}

extern "C" void kernel_launch(void* const* d_in, const int* in_sizes, int n_in,
                              void* d_out, int out_size, void* d_ws, size_t ws_size,
                              hipStream_t stream)
{
    const float* x  = (const float*)d_in[0];
    const float* w1 = (const float*)d_in[1];
    const float* b1 = (const float*)d_in[2];
    const float* w2 = (const float*)d_in[3];
    const float* b2 = (const float*)d_in[4];
    const float* w3 = (const float*)d_in[5];
    const float* b3 = (const float*)d_in[6];
    const float* w4 = (const float*)d_in[7];
    const float* b4 = (const float*)d_in[8];
    const float* w5 = (const float*)d_in[9];
    const float* b5 = (const float*)d_in[10];
    float* out = (float*)d_out;

    float* ws = (float*)d_ws;
    size_t off = 0;
    auto alloc = [&](size_t n) { float* p = ws + off; off += n; return p; };
    float* h1[3]; h1[0] = alloc(524288); h1[1] = alloc(524288); h1[2] = alloc(524288);
    float* c1 = alloc(524288);
    unsigned* p1pk = (unsigned*)alloc(2097152);             // (8,32,16,4,128) u32
    float* h2[3]; h2[0] = alloc(196608); h2[1] = alloc(196608); h2[2] = alloc(196608);
    float* c2 = alloc(196608);
    unsigned short* p2hi = (unsigned short*)alloc(196608);  // 393216 u16
    unsigned short* p2lo = (unsigned short*)alloc(196608);
    float* part = alloc(344064);                            // (12,256,112)
    unsigned short* w1F = (unsigned short*)alloc(24576);    // 49152 u16 (hi)
    unsigned short* w2F = (unsigned short*)alloc(73728);    // 147456 u16 (hi)
    unsigned short* w3F = (unsigned short*)alloc(2359296);  // hi+lo planes
    float* w4T = alloc(32768);
    float* w5T = alloc(11264);
    (void)ws_size; (void)off;  // ~33 MB total

    hipMemsetAsync(h1[2], 0, 524288 * sizeof(float), stream);
    hipMemsetAsync(c1,    0, 524288 * sizeof(float), stream);
    hipMemsetAsync(h2[2], 0, 196608 * sizeof(float), stream);
    hipMemsetAsync(c2,    0, 196608 * sizeof(float), stream);

    prep<<<1420, 256, 0, stream>>>(w1, w2, w3, w4, w5, w1F, w2F, w3F, w4T, w5T);

    for (int t = 0; t < 32; ++t) {
        lstm1_step<<<dim3(4, 8, 8), 512, 0, stream>>>(
            x, w1F, b1, h1[(t + 2) % 3], h1[(t + 1) % 3], h1[t % 3], c1,
            p1pk, t);
    }
    pool1k<<<512, 256, 0, stream>>>(h1[0], h1[1], p1pk, 15); // t=30,31

    for (int t = 0; t < 16; ++t) {
        lstm2_step<<<dim3(8, 4, 8), 256, 0, stream>>>(
            p1pk, w2F, b2, h2[(t + 2) % 3], h2[(t + 1) % 3], c2, h2[t % 3],
            p2hi, p2lo, t);
    }
    pool2<<<192, 256, 0, stream>>>(h2[2], h2[0], p2hi, p2lo, 7);   // t=14,15

    conv3_part<<<dim3(16, 12), 256, 0, stream>>>(p2hi, p2lo, w3F, part);
    head<<<112, 256, 0, stream>>>(part, b3, w4T, b4, w5T, b5, out);
}